// Round 2
// baseline (389.873 us; speedup 1.0000x reference)
//
#include <hip/hip_runtime.h>
#include <math.h>

typedef __attribute__((ext_vector_type(8))) short bf16x8;
typedef __attribute__((ext_vector_type(4))) float f32x4;

#define B_   2
#define L_   2048
#define D_   1024
#define H_   16
#define HD_  64
#define EPS_ 1e-3f
#define ML   (B_*L_)            // 4096 rows
#define NBIG 4096               // QKVG fused width

#define MFMA(a,b,c) __builtin_amdgcn_mfma_f32_16x16x32_bf16((a),(b),(c),0,0,0)

__device__ __forceinline__ unsigned short f2bf(float f) {
    unsigned int x = __float_as_uint(f);
    x += 0x7fffu + ((x >> 16) & 1u);        // round-to-nearest-even
    return (unsigned short)(x >> 16);
}
__device__ __forceinline__ float bf2f(unsigned short u) {
    return __uint_as_float(((unsigned int)u) << 16);
}

// ---------------------------------------------------------------------------
// Weights: fp32 [K=1024][N=1024] -> transposed bf16 hi/lo  WT[w][n][k].
// 5 weights, 64x64 LDS-tile transpose each. grid = 5*256 blocks.
// ---------------------------------------------------------------------------
__global__ __launch_bounds__(256) void conv_weights(
        const float* __restrict__ W0, const float* __restrict__ W1,
        const float* __restrict__ W2, const float* __restrict__ W3,
        const float* __restrict__ W4,
        unsigned short* __restrict__ WTh, unsigned short* __restrict__ WTl) {
    __shared__ float tile[64][65];
    const int bx = blockIdx.x;
    const int w  = bx >> 8;
    const int tn = bx & 255;
    const int k0 = (tn >> 4) * 64;
    const int n0 = (tn & 15) * 64;
    const float* W = (w == 0) ? W0 : (w == 1) ? W1 : (w == 2) ? W2
                   : (w == 3) ? W3 : W4;
    const int t = threadIdx.x;
#pragma unroll
    for (int p = 0; p < 16; p++) {
        int idx = p * 256 + t;
        int r = idx >> 6, c = idx & 63;
        tile[r][c] = W[(size_t)(k0 + r) * 1024 + n0 + c];
    }
    __syncthreads();
#pragma unroll
    for (int p = 0; p < 16; p++) {
        int idx = p * 256 + t;
        int r = idx >> 6, c = idx & 63;
        float v = tile[c][r];                 // = W[k0+c][n0+r]
        size_t o = (size_t)(w * 1024 + n0 + r) * 1024 + k0 + c;
        unsigned short hb = f2bf(v);
        WTh[o] = hb;
        WTl[o] = f2bf(v - bf2f(hb));
    }
}

// ---------------------------------------------------------------------------
// x fp32 -> xh/xl bf16 (row-major, same layout). grid = 4096 blocks.
// ---------------------------------------------------------------------------
__global__ __launch_bounds__(256) void conv_x(const float* __restrict__ x,
        unsigned short* __restrict__ xh, unsigned short* __restrict__ xl) {
    size_t idx = (size_t)(blockIdx.x * 256 + threadIdx.x) * 4;
    float4 v = *(const float4*)&x[idx];
    ushort4 h, lo;
    h.x = f2bf(v.x); lo.x = f2bf(v.x - bf2f(h.x));
    h.y = f2bf(v.y); lo.y = f2bf(v.y - bf2f(h.y));
    h.z = f2bf(v.z); lo.z = f2bf(v.z - bf2f(h.z));
    h.w = f2bf(v.w); lo.w = f2bf(v.w - bf2f(h.w));
    *(ushort4*)&xh[idx] = h;
    *(ushort4*)&xl[idx] = lo;
}

// ---------------------------------------------------------------------------
// Split-bf16 GEMM: C[M][N] fp32 = (Ah+Al)[M][K] @ (Bh+Bl)^T  where B is
// stored TRANSPOSED as [N][K]. C = Ah*Bh + Ah*Bl + Al*Bh (fp32 MFMA acc).
// BM=BN=128, BK=32, 256 thr = 4 waves (2x2), 64x64 per wave, 16x16x32 MFMA.
// ---------------------------------------------------------------------------
__global__ __launch_bounds__(256) void gemm_split(
        const unsigned short* __restrict__ Ah, const unsigned short* __restrict__ Al,
        const unsigned short* __restrict__ Bh, const unsigned short* __restrict__ Bl,
        float* __restrict__ C, int M, int N, int K) {
    __shared__ unsigned short As_h[128][40], As_l[128][40];
    __shared__ unsigned short Bs_h[128][40], Bs_l[128][40];

    const int tid = threadIdx.x;
    const int l  = tid & 63;
    const int w  = tid >> 6;
    const int lg = l >> 4, lr = l & 15;
    const int wr = w >> 1, wc = w & 1;
    const int bm = blockIdx.y * 128, bn = blockIdx.x * 128;

    f32x4 acc[4][4];
#pragma unroll
    for (int mb = 0; mb < 4; mb++)
#pragma unroll
        for (int nb = 0; nb < 4; nb++) acc[mb][nb] = (f32x4){0.f, 0.f, 0.f, 0.f};

    const int srow = tid >> 1;            // 0..127
    const int scol = (tid & 1) * 16;      // 0 or 16

    for (int k0 = 0; k0 < K; k0 += 32) {
        const unsigned short* pAh = Ah + (size_t)(bm + srow) * K + k0 + scol;
        const unsigned short* pAl = Al + (size_t)(bm + srow) * K + k0 + scol;
        const unsigned short* pBh = Bh + (size_t)(bn + srow) * K + k0 + scol;
        const unsigned short* pBl = Bl + (size_t)(bn + srow) * K + k0 + scol;
        bf16x8 ra0 = *(const bf16x8*)pAh;       bf16x8 ra1 = *(const bf16x8*)(pAh + 8);
        bf16x8 rb0 = *(const bf16x8*)pAl;       bf16x8 rb1 = *(const bf16x8*)(pAl + 8);
        bf16x8 rc0 = *(const bf16x8*)pBh;       bf16x8 rc1 = *(const bf16x8*)(pBh + 8);
        bf16x8 rd0 = *(const bf16x8*)pBl;       bf16x8 rd1 = *(const bf16x8*)(pBl + 8);

        __syncthreads();                        // previous iter's reads done
        *(bf16x8*)&As_h[srow][scol]     = ra0;  *(bf16x8*)&As_h[srow][scol + 8] = ra1;
        *(bf16x8*)&As_l[srow][scol]     = rb0;  *(bf16x8*)&As_l[srow][scol + 8] = rb1;
        *(bf16x8*)&Bs_h[srow][scol]     = rc0;  *(bf16x8*)&Bs_h[srow][scol + 8] = rc1;
        *(bf16x8*)&Bs_l[srow][scol]     = rd0;  *(bf16x8*)&Bs_l[srow][scol + 8] = rd1;
        __syncthreads();

        bf16x8 bh_[4], bl_[4];
#pragma unroll
        for (int nb = 0; nb < 4; nb++) {
            bh_[nb] = *(const bf16x8*)&Bs_h[wc * 64 + nb * 16 + lr][lg * 8];
            bl_[nb] = *(const bf16x8*)&Bs_l[wc * 64 + nb * 16 + lr][lg * 8];
        }
#pragma unroll
        for (int mb = 0; mb < 4; mb++) {
            bf16x8 ah_ = *(const bf16x8*)&As_h[wr * 64 + mb * 16 + lr][lg * 8];
            bf16x8 al_ = *(const bf16x8*)&As_l[wr * 64 + mb * 16 + lr][lg * 8];
#pragma unroll
            for (int nb = 0; nb < 4; nb++) {
                f32x4 a = acc[mb][nb];
                a = MFMA(ah_, bh_[nb], a);
                a = MFMA(ah_, bl_[nb], a);
                a = MFMA(al_, bh_[nb], a);
                acc[mb][nb] = a;
            }
        }
    }

#pragma unroll
    for (int mb = 0; mb < 4; mb++)
#pragma unroll
        for (int r = 0; r < 4; r++) {
            size_t row = (size_t)(bm + wr * 64 + mb * 16 + lg * 4 + r);
#pragma unroll
            for (int nb = 0; nb < 4; nb++)
                C[row * N + bn + wc * 64 + nb * 16 + lr] = acc[mb][nb][r];
        }
}

// ---------------------------------------------------------------------------
// RoPE in place on Q (cols 0..1023) and K (cols 1024..2047) of QKVG fp32.
// ---------------------------------------------------------------------------
__global__ __launch_bounds__(256) void rope_inplace(float* __restrict__ QKVG) {
    int idx = blockIdx.x * 256 + threadIdx.x;     // ML*H*32 = 2M
    int dd  = idx & 31;
    int h   = (idx >> 5) & (H_ - 1);
    int row = idx >> 9;
    int tp  = row & (L_ - 1);
    const float C1 = 0.41524101186092029f;        // log2(10000)/32
    float ang = (float)tp * exp2f(-(float)dd * C1);
    float s, c;
    sincosf(ang, &s, &c);
    size_t base = (size_t)row * NBIG;
    int cq = h * HD_ + dd;
    float q1 = QKVG[base + cq], q2 = QKVG[base + cq + 32];
    QKVG[base + cq]      = q1 * c - q2 * s;
    QKVG[base + cq + 32] = q2 * c + q1 * s;
    int ck = 1024 + cq;
    float k1 = QKVG[base + ck], k2 = QKVG[base + ck + 32];
    QKVG[base + ck]      = k1 * c - k2 * s;
    QKVG[base + ck + 32] = k2 * c + k1 * s;
}

// ---------------------------------------------------------------------------
// Retention on MFMA (split bf16) + GroupNorm + SiLU gate.
// Block: 256 thr = 4 waves; wave w owns q-rows [16w,16w+16) of a 64-row tile.
// Reads QKVG fp32 (splits internally), writes Yh/Yl bf16 [4096][1024].
// ---------------------------------------------------------------------------
__global__ __launch_bounds__(256) void retention_mfma(
        const float* __restrict__ QKVG,
        unsigned short* __restrict__ Yh, unsigned short* __restrict__ Yl,
        const float* __restrict__ gng, const float* __restrict__ gnb) {
    __shared__ unsigned short Ksh[64][72], Ksl[64][72];   // K rows x d
    __shared__ unsigned short Vth[64][72], Vtl[64][72];   // d x j (V transposed)
    __shared__ unsigned short Ssh[64][72], Ssl[64][72];   // S rows x j

    const int qt = 31 - blockIdx.y;          // heavy tiles dispatch first
    const int bh = blockIdx.x;
    const int b = bh >> 4, h = bh & (H_ - 1);
    const int tid = threadIdx.x;
    const int l = tid & 63, w = tid >> 6;
    const int lg = l >> 4, lr = l & 15;
    const int rowb = b * L_, q0 = qt * 64, hcol = h * HD_;

    const float l2g = log2f(1.f - exp2f(-(float)(5 + h)));

    float rq[4], ckf[4];
#pragma unroll
    for (int r = 0; r < 4; r++)
        rq[r] = exp2f(l2g * (float)(16 * w + lg * 4 + r));
#pragma unroll
    for (int jb = 0; jb < 4; jb++)
        ckf[jb] = exp2f(-l2g * (float)(16 * jb + lr));

    // Q fragments straight from global (fp32 -> hi/lo bf16), kept in regs
    bf16x8 qh[2], ql[2];
    {
        size_t qrow = (size_t)(rowb + q0 + 16 * w + lr);
#pragma unroll
        for (int ks = 0; ks < 2; ks++) {
            const float* p = &QKVG[qrow * NBIG + hcol + ks * 32 + lg * 8];
            float4 v0 = *(const float4*)p;
            float4 v1 = *(const float4*)(p + 4);
            float vv[8] = {v0.x, v0.y, v0.z, v0.w, v1.x, v1.y, v1.z, v1.w};
            bf16x8 hh, ll;
#pragma unroll
            for (int j = 0; j < 8; j++) {
                unsigned short hb = f2bf(vv[j]);
                hh[j] = (short)hb;
                ll[j] = (short)f2bf(vv[j] - bf2f(hb));
            }
            qh[ks] = hh; ql[ks] = ll;
        }
    }

    f32x4 o4[4];
#pragma unroll
    for (int db = 0; db < 4; db++) o4[db] = (f32x4){0.f, 0.f, 0.f, 0.f};

    const int srow = tid >> 2;          // 0..63
    const int scb  = tid & 3;           // 16-col block

    for (int kt = 0; kt <= qt; kt++) {
        __syncthreads();                // all waves done reading LDS (prev iter)

        // ---- stage K (row-major) and V (transposed), split hi/lo ----
        size_t krow = (size_t)(rowb + kt * 64 + srow) * NBIG;
        const float* pk = &QKVG[krow + 1024 + hcol + scb * 16];
        const float* pv = &QKVG[krow + 2048 + hcol + scb * 16];
#pragma unroll
        for (int half = 0; half < 2; half++) {
            float4 a = *(const float4*)(pk + half * 8);
            float4 b2 = *(const float4*)(pk + half * 8 + 4);
            float kv[8] = {a.x, a.y, a.z, a.w, b2.x, b2.y, b2.z, b2.w};
            bf16x8 hh, ll;
#pragma unroll
            for (int j = 0; j < 8; j++) {
                unsigned short hb = f2bf(kv[j]);
                hh[j] = (short)hb;
                ll[j] = (short)f2bf(kv[j] - bf2f(hb));
            }
            *(bf16x8*)&Ksh[srow][scb * 16 + half * 8] = hh;
            *(bf16x8*)&Ksl[srow][scb * 16 + half * 8] = ll;
        }
        {
            float4 a = *(const float4*)pv;
            float4 b2 = *(const float4*)(pv + 4);
            float4 c2 = *(const float4*)(pv + 8);
            float4 d2 = *(const float4*)(pv + 12);
            float vv[16] = {a.x, a.y, a.z, a.w, b2.x, b2.y, b2.z, b2.w,
                            c2.x, c2.y, c2.z, c2.w, d2.x, d2.y, d2.z, d2.w};
#pragma unroll
            for (int j = 0; j < 16; j++) {
                unsigned short hb = f2bf(vv[j]);
                Vth[scb * 16 + j][srow] = hb;
                Vtl[scb * 16 + j][srow] = f2bf(vv[j] - bf2f(hb));
            }
        }
        __syncthreads();

        // ---- S = Q K^T (split products) ----
        float tf = 0.125f * exp2f(l2g * (float)(64 * (qt - kt)));
        float trq[4];
#pragma unroll
        for (int r = 0; r < 4; r++) trq[r] = tf * rq[r];

        const bool diag = (kt == qt);
#pragma unroll
        for (int jb = 0; jb < 4; jb++) {
            bf16x8 kh0 = *(const bf16x8*)&Ksh[16 * jb + lr][lg * 8];
            bf16x8 kh1 = *(const bf16x8*)&Ksh[16 * jb + lr][32 + lg * 8];
            bf16x8 kl0 = *(const bf16x8*)&Ksl[16 * jb + lr][lg * 8];
            bf16x8 kl1 = *(const bf16x8*)&Ksl[16 * jb + lr][32 + lg * 8];
            f32x4 s4 = (f32x4){0.f, 0.f, 0.f, 0.f};
            s4 = MFMA(qh[0], kh0, s4);
            s4 = MFMA(qh[1], kh1, s4);
            s4 = MFMA(qh[0], kl0, s4);
            s4 = MFMA(qh[1], kl1, s4);
            s4 = MFMA(ql[0], kh0, s4);
            s4 = MFMA(ql[1], kh1, s4);
            // decay + causal mask + split into LDS
#pragma unroll
            for (int r = 0; r < 4; r++) {
                float sv = s4[r] * trq[r] * ckf[jb];
                if (diag) {
                    int d = (16 * w + lg * 4 + r) - (16 * jb + lr);
                    if (d < 0) sv = 0.f;
                }
                unsigned short hb = f2bf(sv);
                Ssh[16 * w + lg * 4 + r][16 * jb + lr] = hb;
                Ssl[16 * w + lg * 4 + r][16 * jb + lr] = f2bf(sv - bf2f(hb));
            }
        }
        // intra-wave LDS dependency (same wave wrote these rows); compiler
        // inserts the lgkmcnt wait for the aliasing shared arrays.

        // ---- O += S V ----
        bf16x8 sh0 = *(const bf16x8*)&Ssh[16 * w + lr][lg * 8];
        bf16x8 sh1 = *(const bf16x8*)&Ssh[16 * w + lr][32 + lg * 8];
        bf16x8 sl0 = *(const bf16x8*)&Ssl[16 * w + lr][lg * 8];
        bf16x8 sl1 = *(const bf16x8*)&Ssl[16 * w + lr][32 + lg * 8];
#pragma unroll
        for (int db = 0; db < 4; db++) {
            bf16x8 vh0 = *(const bf16x8*)&Vth[16 * db + lr][lg * 8];
            bf16x8 vh1 = *(const bf16x8*)&Vth[16 * db + lr][32 + lg * 8];
            bf16x8 vl0 = *(const bf16x8*)&Vtl[16 * db + lr][lg * 8];
            bf16x8 vl1 = *(const bf16x8*)&Vtl[16 * db + lr][32 + lg * 8];
            f32x4 a = o4[db];
            a = MFMA(sh0, vh0, a);
            a = MFMA(sh1, vh1, a);
            a = MFMA(sh0, vl0, a);
            a = MFMA(sh1, vl1, a);
            a = MFMA(sl0, vh0, a);
            a = MFMA(sl1, vh1, a);
            o4[db] = a;
        }
    }

    // ---- GroupNorm over the 64 head-dims of each row + SiLU gate ----
    float sum[4], sq[4];
#pragma unroll
    for (int r = 0; r < 4; r++) {
        float s_ = 0.f, q_ = 0.f;
#pragma unroll
        for (int db = 0; db < 4; db++) { float v = o4[db][r]; s_ += v; q_ += v * v; }
        sum[r] = s_; sq[r] = q_;
    }
#pragma unroll
    for (int m = 1; m < 16; m <<= 1) {
#pragma unroll
        for (int r = 0; r < 4; r++) {
            sum[r] += __shfl_xor(sum[r], m);
            sq[r]  += __shfl_xor(sq[r], m);
        }
    }
#pragma unroll
    for (int r = 0; r < 4; r++) {
        float mean = sum[r] * (1.f / 64.f);
        float var  = sq[r] * (1.f / 64.f) - mean * mean;
        float rstd = rsqrtf(var + EPS_);
        size_t row = (size_t)(rowb + q0 + 16 * w + lg * 4 + r);
#pragma unroll
        for (int db = 0; db < 4; db++) {
            int c = db * 16 + lr;
            float g = QKVG[row * NBIG + 3072 + hcol + c];
            float y = (o4[db][r] - mean) * rstd * gng[hcol + c] + gnb[hcol + c];
            float sig = 1.f / (1.f + expf(-g));
            float res = y * g * sig;
            unsigned short hb = f2bf(res);
            Yh[row * 1024 + hcol + c] = hb;
            Yl[row * 1024 + hcol + c] = f2bf(res - bf2f(hb));
        }
    }
}

// ---------------------------------------------------------------------------
// ws layout (100 MB):
//   0      QKVG fp32 [4096][4096]            64 MB
//   64MB   xh  bf16 [4096][1024]  (-> Yh)     8 MB
//   72MB   xl  bf16 [4096][1024]  (-> Yl)     8 MB
//   80MB   WTh bf16 [5][1024][1024]          10 MB
//   90MB   WTl bf16 [5][1024][1024]          10 MB
// ---------------------------------------------------------------------------
extern "C" void kernel_launch(void* const* d_in, const int* in_sizes, int n_in,
                              void* d_out, int out_size, void* d_ws, size_t ws_size,
                              hipStream_t stream) {
    const float* x   = (const float*)d_in[0];
    const float* Wq  = (const float*)d_in[1];
    const float* Wk  = (const float*)d_in[2];
    const float* Wv  = (const float*)d_in[3];
    const float* Wg  = (const float*)d_in[4];
    const float* Wo  = (const float*)d_in[5];
    const float* gng = (const float*)d_in[6];
    const float* gnb = (const float*)d_in[7];

    char* ws = (char*)d_ws;
    float*          QKVG = (float*)ws;
    unsigned short* xh   = (unsigned short*)(ws + (size_t)64 * 1024 * 1024);
    unsigned short* xl   = (unsigned short*)(ws + (size_t)72 * 1024 * 1024);
    unsigned short* WTh  = (unsigned short*)(ws + (size_t)80 * 1024 * 1024);
    unsigned short* WTl  = (unsigned short*)(ws + (size_t)90 * 1024 * 1024);
    unsigned short* Yh   = xh;   // x is dead after the projection GEMM
    unsigned short* Yl   = xl;

    conv_weights<<<5 * 256, 256, 0, stream>>>(Wq, Wk, Wv, Wg, Wo, WTh, WTl);
    conv_x<<<(ML * D_) / (256 * 4), 256, 0, stream>>>(x, xh, xl);

    // fused projections: [4096,1024] @ [1024,4096] -> QKVG [4096][4096]
    gemm_split<<<dim3(NBIG / 128, ML / 128), 256, 0, stream>>>(
        xh, xl, WTh, WTl, QKVG, ML, NBIG, D_);

    rope_inplace<<<(ML * H_ * (HD_ / 2)) / 256, 256, 0, stream>>>(QKVG);

    retention_mfma<<<dim3(B_ * H_, L_ / 64), 256, 0, stream>>>(
        QKVG, Yh, Yl, gng, gnb);

    // out = Y @ Wo : [4096,1024] @ [1024,1024] -> d_out fp32
    gemm_split<<<dim3(D_ / 128, ML / 128), 256, 0, stream>>>(
        Yh, Yl, WTh + (size_t)4 * 1024 * 1024, WTl + (size_t)4 * 1024 * 1024,
        (float*)d_out, ML, D_, D_);
}